// Round 1
// baseline (417.528 us; speedup 1.0000x reference)
//
#include <hip/hip_runtime.h>

#define FFT_N    1024
#define FFT_LOGN 10

__device__ __forceinline__ unsigned int f2key(float f) {
    unsigned int u = __float_as_uint(f);
    // monotone map: float order -> uint order
    return (u & 0x80000000u) ? ~u : (u | 0x80000000u);
}
__device__ __forceinline__ float key2f(unsigned int k) {
    unsigned int u = (k & 0x80000000u) ? (k & 0x7FFFFFFFu) : ~k;
    return __uint_as_float(u);
}

__global__ void init_mm(unsigned int* mm) {
    mm[0] = 0xFFFFFFFFu; // running-min key
    mm[1] = 0u;          // running-max key
}

__global__ __launch_bounds__(256) void ifft_rows(const float* __restrict__ x,
                                                 float* __restrict__ out,
                                                 unsigned int* __restrict__ mm) {
    __shared__ float sre[FFT_N];
    __shared__ float sim[FFT_N];
    __shared__ float wredmin[4], wredmax[4];

    const int row = blockIdx.x;       // 0 .. 16383
    const int b   = row >> 10;        // batch
    const int p   = row & 1023;       // projection row
    const float* re = x + (((size_t)b * 2 + 0) * 1024 + p) * 1024;
    const float* im = x + (((size_t)b * 2 + 1) * 1024 + p) * 1024;
    const int t = threadIdx.x;

    // Coalesced global load, bit-reversed LDS scatter.
    #pragma unroll
    for (int q = 0; q < 4; ++q) {
        int i = t + q * 256;
        int r = (int)(__brev((unsigned)i) >> (32 - FFT_LOGN));
        sre[r] = re[i];
        sim[r] = im[i];
    }
    __syncthreads();

    // Iterative radix-2 DIT, inverse transform (twiddle e^{+i*2pi*j/len}).
    // All 512 butterflies in a stage touch disjoint (p0,p1) pairs -> only
    // a barrier between stages is needed.
    #pragma unroll
    for (int s = 1; s <= FFT_LOGN; ++s) {
        const int half = 1 << (s - 1);
        #pragma unroll
        for (int q = 0; q < 2; ++q) {
            int bfly = t + q * 256;
            int j  = bfly & (half - 1);
            int p0 = ((bfly >> (s - 1)) << s) | j;
            int p1 = p0 + half;
            float ang = (6.283185307179586f / (float)(1 << s)) * (float)j;
            float wi, wr;
            __sincosf(ang, &wi, &wr);     // wi = sin, wr = cos
            float ar = sre[p0], ai = sim[p0];
            float br = sre[p1], bi = sim[p1];
            float tr = wr * br - wi * bi;
            float ti = wr * bi + wi * br;
            sre[p0] = ar + tr; sim[p0] = ai + ti;
            sre[p1] = ar - tr; sim[p1] = ai - ti;
        }
        __syncthreads();
    }

    // Scale 1/N, ifftshift sign (-1)^n, store, track min/max.
    float lmin = INFINITY, lmax = -INFINITY;
    float* orow = out + (size_t)row * FFT_N;
    #pragma unroll
    for (int q = 0; q < 4; ++q) {
        int i = t + q * 256;
        float v = sre[i] * (1.0f / FFT_N);
        v = (i & 1) ? -v : v;
        orow[i] = v;
        lmin = fminf(lmin, v);
        lmax = fmaxf(lmax, v);
    }

    // Wave-64 shuffle reduction, then cross-wave via LDS, one atomic pair per block.
    #pragma unroll
    for (int off = 32; off > 0; off >>= 1) {
        lmin = fminf(lmin, __shfl_down(lmin, off));
        lmax = fmaxf(lmax, __shfl_down(lmax, off));
    }
    const int wid = t >> 6;
    if ((t & 63) == 0) { wredmin[wid] = lmin; wredmax[wid] = lmax; }
    __syncthreads();
    if (t == 0) {
        float m = fminf(fminf(wredmin[0], wredmin[1]), fminf(wredmin[2], wredmin[3]));
        float M = fmaxf(fmaxf(wredmax[0], wredmax[1]), fmaxf(wredmax[2], wredmax[3]));
        atomicMin(&mm[0], f2key(m));
        atomicMax(&mm[1], f2key(M));
    }
}

__global__ __launch_bounds__(256) void normalize_k(float* __restrict__ out,
                                                   const unsigned int* __restrict__ mm,
                                                   int n4) {
    const float mn  = key2f(mm[0]);
    const float mx  = key2f(mm[1]);
    const float inv = 1.0f / (mx - mn);
    float4* o4 = reinterpret_cast<float4*>(out);
    for (int i = blockIdx.x * blockDim.x + threadIdx.x; i < n4;
         i += gridDim.x * blockDim.x) {
        float4 v = o4[i];
        v.x = (v.x - mn) * inv;
        v.y = (v.y - mn) * inv;
        v.z = (v.z - mn) * inv;
        v.w = (v.w - mn) * inv;
        o4[i] = v;
    }
}

extern "C" void kernel_launch(void* const* d_in, const int* in_sizes, int n_in,
                              void* d_out, int out_size, void* d_ws, size_t ws_size,
                              hipStream_t stream) {
    const float* x = (const float*)d_in[0];
    float* out = (float*)d_out;
    unsigned int* mm = (unsigned int*)d_ws;

    hipLaunchKernelGGL(init_mm, dim3(1), dim3(1), 0, stream, mm);
    hipLaunchKernelGGL(ifft_rows, dim3(16384), dim3(256), 0, stream, x, out, mm);
    const int n4 = out_size / 4;  // 16,777,216 / 4
    hipLaunchKernelGGL(normalize_k, dim3(2048), dim3(256), 0, stream, out, mm, n4);
}

// Round 2
// 73.376 us; speedup vs baseline: 5.6902x; 5.6902x over previous
//
#include <hip/hip_runtime.h>

#define FFT_N   1024
#define NPART   4096        // ifft grid: 4 rows (waves) per 256-thread block

__device__ __forceinline__ int br6(int x) { return (int)(__brev((unsigned)x) >> 26); }

__device__ __forceinline__ unsigned int f2key(float f) {
    unsigned int u = __float_as_uint(f);
    return (u & 0x80000000u) ? ~u : (u | 0x80000000u);
}
__device__ __forceinline__ float key2f(unsigned int k) {
    unsigned int u = (k & 0x80000000u) ? (k & 0x7FFFFFFFu) : ~k;
    return __uint_as_float(u);
}

__global__ void init_mm(unsigned int* mm) {
    mm[0] = 0xFFFFFFFFu;
    mm[1] = 0u;
}

// W16^e = e^{+2*pi*i*e/16} (inverse-transform sign), e = a*c in {0,1,2,3,4,6,9}
__device__ __constant__ float W16R[10] = {
    1.0f, 0.92387953251f, 0.70710678119f, 0.38268343236f, 0.0f,
    0.0f, -0.70710678119f, 0.0f, 0.0f, -0.92387953251f };
__device__ __constant__ float W16I[10] = {
    0.0f, 0.38268343236f, 0.70710678119f, 0.92387953251f, 1.0f,
    0.0f, 0.70710678119f, 0.0f, 0.0f, -0.38268343236f };

template <bool USE_ATOMIC>
__global__ __launch_bounds__(256) void ifft_rows(const float* __restrict__ x,
                                                 float* __restrict__ out,
                                                 float* __restrict__ partials,
                                                 unsigned int* __restrict__ mm) {
    const int t    = threadIdx.x;
    const int lane = t & 63;
    const int wid  = t >> 6;
    const int row  = blockIdx.x * 4 + wid;   // 0 .. 16383
    const int b    = row >> 10;
    const int p    = row & 1023;
    const float* re = x + (((size_t)(b * 2) * 1024) + p) * 1024;
    const float* im = re + (size_t)1024 * 1024;

    const int n1 = br6(lane);

    // ---- load: lane holds x[n1 + 64*r] for r=0..15 (bit-reversed lane map) ----
    float xr[16], xi[16];
    #pragma unroll
    for (int r = 0; r < 16; ++r) {
        xr[r] = re[n1 + 64 * r];
        xi[r] = im[n1 + 64 * r];
    }

    // ---- in-register 16-point inverse DFT over r (= n2) ----
    // n2 = a + 4b ; first: 4-pt DFT over b for each a, store y[a + 4c]
    float yr[16], yi[16];
    #pragma unroll
    for (int a = 0; a < 4; ++a) {
        float t0r = xr[a] + xr[a + 8],      t0i = xi[a] + xi[a + 8];
        float t1r = xr[a] - xr[a + 8],      t1i = xi[a] - xi[a + 8];
        float t2r = xr[a + 4] + xr[a + 12], t2i = xi[a + 4] + xi[a + 12];
        float t3r = xr[a + 4] - xr[a + 12], t3i = xi[a + 4] - xi[a + 12];
        yr[a]      = t0r + t2r;  yi[a]      = t0i + t2i;   // c=0
        yr[a + 4]  = t1r - t3i;  yi[a + 4]  = t1i + t3r;   // c=1: t1 + i*t3
        yr[a + 8]  = t0r - t2r;  yi[a + 8]  = t0i - t2i;   // c=2
        yr[a + 12] = t1r + t3i;  yi[a + 12] = t1i - t3r;   // c=3: t1 - i*t3
    }
    // second: for each c, twiddle W16^{a*c} then 4-pt DFT over a -> A[c + 4d]
    float ar_[16], ai_[16];
    #pragma unroll
    for (int c = 0; c < 4; ++c) {
        float zr[4], zi[4];
        #pragma unroll
        for (int a = 0; a < 4; ++a) {
            float wr = W16R[a * c], wi = W16I[a * c];
            float vr = yr[a + 4 * c], vi = yi[a + 4 * c];
            zr[a] = vr * wr - vi * wi;
            zi[a] = vr * wi + vi * wr;
        }
        float u0r = zr[0] + zr[2], u0i = zi[0] + zi[2];
        float u1r = zr[0] - zr[2], u1i = zi[0] - zi[2];
        float u2r = zr[1] + zr[3], u2i = zi[1] + zi[3];
        float u3r = zr[1] - zr[3], u3i = zi[1] - zi[3];
        ar_[c]      = u0r + u2r;  ai_[c]      = u0i + u2i;
        ar_[c + 4]  = u1r - u3i;  ai_[c + 4]  = u1i + u3r;
        ar_[c + 8]  = u0r - u2r;  ai_[c + 8]  = u0i - u2i;
        ar_[c + 12] = u1r + u3i;  ai_[c + 12] = u1i - u3r;
    }

    // ---- per-lane twiddle: B[k2] = A[k2] * e^{+i * 2pi * n1 * k2 / 1024} ----
    const float theta = 6.283185307179586f * (float)n1 * (1.0f / 1024.0f);
    #pragma unroll
    for (int k2 = 1; k2 < 16; ++k2) {
        float s, c;
        __sincosf(theta * (float)k2, &s, &c);
        float vr = ar_[k2], vi = ai_[k2];
        ar_[k2] = vr * c - vi * s;
        ai_[k2] = vr * s + vi * c;
    }

    // ---- 64-point cross-lane inverse DFT: radix-2 DIT, bit-reversed input,
    //      natural output. 6 stages of shfl_xor; stage twiddle shared by all regs.
    #pragma unroll
    for (int st = 0; st < 6; ++st) {
        const int h = 1 << st;
        const bool odd = (lane & h) != 0;
        float ang = odd ? (3.14159265358979f * (float)(lane & (h - 1)) / (float)h) : 0.0f;
        float ws, wc;
        __sincosf(ang, &ws, &wc);         // odd: W_{2h}^{j}; even: (1,0)
        const float s = odd ? -1.0f : 1.0f;
        if (st < 5) {
            #pragma unroll
            for (int r = 0; r < 16; ++r) {
                float tr = ar_[r] * wc - ai_[r] * ws;
                float ti = ar_[r] * ws + ai_[r] * wc;
                float pr = __shfl_xor(tr, h);
                float pi = __shfl_xor(ti, h);
                ar_[r] = fmaf(s, tr, pr);
                ai_[r] = fmaf(s, ti, pi);
            }
        } else {
            // last stage: only the real part of the output is needed
            #pragma unroll
            for (int r = 0; r < 16; ++r) {
                float tr = ar_[r] * wc - ai_[r] * ws;
                float pr = __shfl_xor(tr, h);
                ar_[r] = fmaf(s, tr, pr);
            }
        }
    }

    // ---- epilogue: scale 1/N, ifftshift sign (-1)^k with k = 16*lane + k2 ----
    float vals[16];
    float vmin = INFINITY, vmax = -INFINITY;
    #pragma unroll
    for (int k2 = 0; k2 < 16; ++k2) {
        float v = ar_[k2] * ((k2 & 1) ? -9.765625e-4f : 9.765625e-4f);
        vals[k2] = v;
        vmin = fminf(vmin, v);
        vmax = fmaxf(vmax, v);
    }
    float* orow = out + (size_t)row * FFT_N;
    #pragma unroll
    for (int q = 0; q < 4; ++q) {
        *reinterpret_cast<float4*>(orow + 16 * lane + 4 * q) =
            make_float4(vals[4 * q], vals[4 * q + 1], vals[4 * q + 2], vals[4 * q + 3]);
    }

    // ---- min/max: wave butterfly reduce, cross-wave via LDS, 1 write per block ----
    #pragma unroll
    for (int off = 32; off >= 1; off >>= 1) {
        vmin = fminf(vmin, __shfl_xor(vmin, off));
        vmax = fmaxf(vmax, __shfl_xor(vmax, off));
    }
    __shared__ float smn[4], smx[4];
    if ((t & 63) == 0) { smn[wid] = vmin; smx[wid] = vmax; }
    __syncthreads();
    if (t == 0) {
        float mn = fminf(fminf(smn[0], smn[1]), fminf(smn[2], smn[3]));
        float mx = fmaxf(fmaxf(smx[0], smx[1]), fmaxf(smx[2], smx[3]));
        if (USE_ATOMIC) {
            atomicMin(&mm[0], f2key(mn));
            atomicMax(&mm[1], f2key(mx));
        } else {
            partials[2 * blockIdx.x]     = mn;
            partials[2 * blockIdx.x + 1] = mx;
        }
    }
}

__global__ __launch_bounds__(256) void reduce_mm(const float* __restrict__ partials,
                                                 float* __restrict__ mm) {
    float mn = INFINITY, mx = -INFINITY;
    for (int i = threadIdx.x; i < NPART; i += 256) {
        float2 v = reinterpret_cast<const float2*>(partials)[i];
        mn = fminf(mn, v.x);
        mx = fmaxf(mx, v.y);
    }
    #pragma unroll
    for (int off = 32; off >= 1; off >>= 1) {
        mn = fminf(mn, __shfl_xor(mn, off));
        mx = fmaxf(mx, __shfl_xor(mx, off));
    }
    __shared__ float smn[4], smx[4];
    const int wid = threadIdx.x >> 6;
    if ((threadIdx.x & 63) == 0) { smn[wid] = mn; smx[wid] = mx; }
    __syncthreads();
    if (threadIdx.x == 0) {
        mm[0] = fminf(fminf(smn[0], smn[1]), fminf(smn[2], smn[3]));
        mm[1] = fmaxf(fmaxf(smx[0], smx[1]), fmaxf(smx[2], smx[3]));
    }
}

template <bool FROM_KEYS>
__global__ __launch_bounds__(256) void normalize_k(float* __restrict__ out,
                                                   const void* __restrict__ mmv,
                                                   int n4) {
    float mn, mx;
    if (FROM_KEYS) {
        const unsigned int* mm = (const unsigned int*)mmv;
        mn = key2f(mm[0]); mx = key2f(mm[1]);
    } else {
        const float* mm = (const float*)mmv;
        mn = mm[0]; mx = mm[1];
    }
    const float inv = 1.0f / (mx - mn);
    float4* o4 = reinterpret_cast<float4*>(out);
    for (int i = blockIdx.x * blockDim.x + threadIdx.x; i < n4;
         i += gridDim.x * blockDim.x) {
        float4 v = o4[i];
        v.x = (v.x - mn) * inv;
        v.y = (v.y - mn) * inv;
        v.z = (v.z - mn) * inv;
        v.w = (v.w - mn) * inv;
        o4[i] = v;
    }
}

extern "C" void kernel_launch(void* const* d_in, const int* in_sizes, int n_in,
                              void* d_out, int out_size, void* d_ws, size_t ws_size,
                              hipStream_t stream) {
    const float* x = (const float*)d_in[0];
    float* out = (float*)d_out;
    const int n4 = out_size / 4;

    if (ws_size >= (size_t)(2 * NPART + 2) * sizeof(float)) {
        float* partials = (float*)d_ws;
        float* mm = partials + 2 * NPART;
        hipLaunchKernelGGL((ifft_rows<false>), dim3(NPART), dim3(256), 0, stream,
                           x, out, partials, nullptr);
        hipLaunchKernelGGL(reduce_mm, dim3(1), dim3(256), 0, stream, partials, mm);
        hipLaunchKernelGGL((normalize_k<false>), dim3(2048), dim3(256), 0, stream,
                           out, (const void*)mm, n4);
    } else {
        unsigned int* mm = (unsigned int*)d_ws;
        hipLaunchKernelGGL(init_mm, dim3(1), dim3(1), 0, stream, mm);
        hipLaunchKernelGGL((ifft_rows<true>), dim3(NPART), dim3(256), 0, stream,
                           x, out, nullptr, mm);
        hipLaunchKernelGGL((normalize_k<true>), dim3(2048), dim3(256), 0, stream,
                           out, (const void*)mm, n4);
    }
}

// Round 3
// 72.691 us; speedup vs baseline: 5.7439x; 1.0094x over previous
//
#include <hip/hip_runtime.h>

#define FFT_N 1024
#define NPART 4096        // 4 rows (waves) per 256-thread block

__device__ __forceinline__ int br6(int x) { return (int)(__brev((unsigned)x) >> 26); }

__device__ __forceinline__ unsigned int f2key(float f) {
    unsigned int u = __float_as_uint(f);
    return (u & 0x80000000u) ? ~u : (u | 0x80000000u);
}
__device__ __forceinline__ float key2f(unsigned int k) {
    unsigned int u = (k & 0x80000000u) ? (k & 0x7FFFFFFFu) : ~k;
    return __uint_as_float(u);
}

__global__ void init_mm(unsigned int* mm) {
    mm[0] = 0xFFFFFFFFu;
    mm[1] = 0u;
}

template <bool USE_ATOMIC>
__global__ __launch_bounds__(256) void ifft_rows(const float* __restrict__ x,
                                                 float* __restrict__ out,
                                                 float* __restrict__ partials,
                                                 unsigned int* __restrict__ mm) {
    const int t    = threadIdx.x;
    const int lane = t & 63;
    const int wid  = t >> 6;
    const int row  = blockIdx.x * 4 + wid;   // 0 .. 16383
    const int b    = row >> 10;
    const int p    = row & 1023;
    const float* re = x + (((size_t)(b * 2) * 1024) + p) * 1024;
    const float* im = re + (size_t)1024 * 1024;

    // ---- load: lane holds c[16*lane + r], r=0..15 -> 8x dwordx4, coalesced ----
    float ar[16], ai[16];
    #pragma unroll
    for (int q = 0; q < 4; ++q) {
        float4 v = *reinterpret_cast<const float4*>(re + 16 * lane + 4 * q);
        ar[4 * q] = v.x; ar[4 * q + 1] = v.y; ar[4 * q + 2] = v.z; ar[4 * q + 3] = v.w;
    }
    #pragma unroll
    for (int q = 0; q < 4; ++q) {
        float4 w = *reinterpret_cast<const float4*>(im + 16 * lane + 4 * q);
        ai[4 * q] = w.x; ai[4 * q + 1] = w.y; ai[4 * q + 2] = w.z; ai[4 * q + 3] = w.w;
    }

    // ---- 64-pt inverse DFT across lanes, radix-2 DIF: natural in, bit-rev out.
    //      Stage h: pairs lane ^ h; high lane gets (partner - self) * e^{+i*pi*j/h}.
    #pragma unroll
    for (int st = 0; st < 6; ++st) {
        const int h  = 32 >> st;
        const bool hi = (lane & h) != 0;
        const float s = hi ? -1.0f : 1.0f;
        if (h > 1) {
            const int j = lane & (h - 1);
            float ang = hi ? (3.14159265358979323846f / (float)h) * (float)j : 0.0f;
            float ws, wc;
            __sincosf(ang, &ws, &wc);    // low lanes: (0,1) -> identity twiddle
            #pragma unroll
            for (int r = 0; r < 16; ++r) {
                float pr = __shfl_xor(ar[r], h);
                float pi = __shfl_xor(ai[r], h);
                float tr = fmaf(s, ar[r], pr);
                float ti = fmaf(s, ai[r], pi);
                ar[r] = tr * wc - ti * ws;
                ai[r] = tr * ws + ti * wc;
            }
        } else {
            #pragma unroll
            for (int r = 0; r < 16; ++r) {
                float pr = __shfl_xor(ar[r], 1);
                float pi = __shfl_xor(ai[r], 1);
                ar[r] = fmaf(s, ar[r], pr);
                ai[r] = fmaf(s, ai[r], pi);
            }
        }
    }

    // ---- per-lane twiddle: B[r] = A[r] * e^{+i*2*pi*r*k1/1024}, k1 = br6(lane) ----
    const int k1 = br6(lane);
    const float theta = 6.283185307179586f * (float)k1 * (1.0f / 1024.0f);
    #pragma unroll
    for (int r = 1; r < 16; ++r) {
        float sn, cs;
        __sincosf(theta * (float)r, &sn, &cs);
        float vr = ar[r], vi = ai[r];
        ar[r] = vr * cs - vi * sn;
        ai[r] = vr * sn + vi * cs;
    }

    // ---- in-register 16-pt inverse DFT over r; only real parts of outputs ----
    // layer 1: 4-pt DFT over b (r = a + 4b) -> y[a + 4c]
    float yr[16], yi[16];
    #pragma unroll
    for (int a = 0; a < 4; ++a) {
        float t0r = ar[a] + ar[a + 8],      t0i = ai[a] + ai[a + 8];
        float t1r = ar[a] - ar[a + 8],      t1i = ai[a] - ai[a + 8];
        float t2r = ar[a + 4] + ar[a + 12], t2i = ai[a + 4] + ai[a + 12];
        float t3r = ar[a + 4] - ar[a + 12], t3i = ai[a + 4] - ai[a + 12];
        yr[a]      = t0r + t2r;  yi[a]      = t0i + t2i;
        yr[a + 4]  = t1r - t3i;  yi[a + 4]  = t1i + t3r;
        yr[a + 8]  = t0r - t2r;  yi[a + 8]  = t0i - t2i;
        yr[a + 12] = t1r + t3i;  yi[a + 12] = t1i - t3r;
    }
    // layer 2: twiddle W16^{a*c} (constexpr, folded) + 4-pt over a, real out only
    constexpr float W16R_[10] = { 1.0f, 0.92387953251f, 0.70710678119f, 0.38268343236f,
                                  0.0f, 0.0f, -0.70710678119f, 0.0f, 0.0f, -0.92387953251f };
    constexpr float W16I_[10] = { 0.0f, 0.38268343236f, 0.70710678119f, 0.92387953251f,
                                  1.0f, 0.0f, 0.70710678119f, 0.0f, 0.0f, -0.38268343236f };
    float vals[16];
    const float scale = (lane & 32) ? -9.765625e-4f : 9.765625e-4f;  // (-1)^{br6(lane)} / 1024
    #pragma unroll
    for (int c = 0; c < 4; ++c) {
        float zr0 = yr[4 * c];                                   // a=0: W=1, zi0 unused
        float zr1, zi1, zr2, zr3, zi3;
        { float wr = W16R_[c],     wi = W16I_[c];
          float vr = yr[1 + 4 * c], vi = yi[1 + 4 * c];
          zr1 = vr * wr - vi * wi; zi1 = vr * wi + vi * wr; }
        { float wr = W16R_[2 * c], wi = W16I_[2 * c];
          float vr = yr[2 + 4 * c], vi = yi[2 + 4 * c];
          zr2 = vr * wr - vi * wi; }                             // zi2 unused
        { float wr = W16R_[3 * c], wi = W16I_[3 * c];
          float vr = yr[3 + 4 * c], vi = yi[3 + 4 * c];
          zr3 = vr * wr - vi * wi; zi3 = vr * wi + vi * wr; }
        float u0r = zr0 + zr2, u1r = zr0 - zr2;
        float u2r = zr1 + zr3;
        float u3i = zi1 - zi3;
        vals[c]      = (u0r + u2r) * scale;
        vals[c + 4]  = (u1r - u3i) * scale;
        vals[c + 8]  = (u0r - u2r) * scale;
        vals[c + 12] = (u1r + u3i) * scale;
    }

    // ---- store: out[k1 + 64*k2]; each instr covers one 256B segment ----
    float vmin = INFINITY, vmax = -INFINITY;
    #pragma unroll
    for (int k2 = 0; k2 < 16; ++k2) {
        vmin = fminf(vmin, vals[k2]);
        vmax = fmaxf(vmax, vals[k2]);
    }
    float* orow = out + (size_t)row * FFT_N;
    #pragma unroll
    for (int k2 = 0; k2 < 16; ++k2) {
        orow[k1 + (k2 << 6)] = vals[k2];
    }

    // ---- min/max: wave butterfly, cross-wave via LDS, one write per block ----
    #pragma unroll
    for (int off = 32; off >= 1; off >>= 1) {
        vmin = fminf(vmin, __shfl_xor(vmin, off));
        vmax = fmaxf(vmax, __shfl_xor(vmax, off));
    }
    __shared__ float smn[4], smx[4];
    if ((t & 63) == 0) { smn[wid] = vmin; smx[wid] = vmax; }
    __syncthreads();
    if (t == 0) {
        float mn = fminf(fminf(smn[0], smn[1]), fminf(smn[2], smn[3]));
        float mx = fmaxf(fmaxf(smx[0], smx[1]), fmaxf(smx[2], smx[3]));
        if (USE_ATOMIC) {
            atomicMin(&mm[0], f2key(mn));
            atomicMax(&mm[1], f2key(mx));
        } else {
            partials[2 * blockIdx.x]     = mn;
            partials[2 * blockIdx.x + 1] = mx;
        }
    }
}

__global__ __launch_bounds__(256) void reduce_mm(const float* __restrict__ partials,
                                                 float* __restrict__ mm) {
    float mn = INFINITY, mx = -INFINITY;
    for (int i = threadIdx.x; i < NPART; i += 256) {
        float2 v = reinterpret_cast<const float2*>(partials)[i];
        mn = fminf(mn, v.x);
        mx = fmaxf(mx, v.y);
    }
    #pragma unroll
    for (int off = 32; off >= 1; off >>= 1) {
        mn = fminf(mn, __shfl_xor(mn, off));
        mx = fmaxf(mx, __shfl_xor(mx, off));
    }
    __shared__ float smn[4], smx[4];
    const int wid = threadIdx.x >> 6;
    if ((threadIdx.x & 63) == 0) { smn[wid] = mn; smx[wid] = mx; }
    __syncthreads();
    if (threadIdx.x == 0) {
        mm[0] = fminf(fminf(smn[0], smn[1]), fminf(smn[2], smn[3]));
        mm[1] = fmaxf(fmaxf(smx[0], smx[1]), fmaxf(smx[2], smx[3]));
    }
}

template <bool FROM_KEYS>
__global__ __launch_bounds__(256) void normalize_k(float* __restrict__ out,
                                                   const void* __restrict__ mmv,
                                                   int n4) {
    float mn, mx;
    if (FROM_KEYS) {
        const unsigned int* mm = (const unsigned int*)mmv;
        mn = key2f(mm[0]); mx = key2f(mm[1]);
    } else {
        const float* mm = (const float*)mmv;
        mn = mm[0]; mx = mm[1];
    }
    const float inv = 1.0f / (mx - mn);
    float4* o4 = reinterpret_cast<float4*>(out);
    for (int i = blockIdx.x * blockDim.x + threadIdx.x; i < n4;
         i += gridDim.x * blockDim.x) {
        float4 v = o4[i];
        v.x = (v.x - mn) * inv;
        v.y = (v.y - mn) * inv;
        v.z = (v.z - mn) * inv;
        v.w = (v.w - mn) * inv;
        o4[i] = v;
    }
}

extern "C" void kernel_launch(void* const* d_in, const int* in_sizes, int n_in,
                              void* d_out, int out_size, void* d_ws, size_t ws_size,
                              hipStream_t stream) {
    const float* x = (const float*)d_in[0];
    float* out = (float*)d_out;
    const int n4 = out_size / 4;

    if (ws_size >= (size_t)(2 * NPART + 2) * sizeof(float)) {
        float* partials = (float*)d_ws;
        float* mm = partials + 2 * NPART;
        hipLaunchKernelGGL((ifft_rows<false>), dim3(NPART), dim3(256), 0, stream,
                           x, out, partials, nullptr);
        hipLaunchKernelGGL(reduce_mm, dim3(1), dim3(256), 0, stream, partials, mm);
        hipLaunchKernelGGL((normalize_k<false>), dim3(2048), dim3(256), 0, stream,
                           out, (const void*)mm, n4);
    } else {
        unsigned int* mm = (unsigned int*)d_ws;
        hipLaunchKernelGGL(init_mm, dim3(1), dim3(1), 0, stream, mm);
        hipLaunchKernelGGL((ifft_rows<true>), dim3(NPART), dim3(256), 0, stream,
                           x, out, nullptr, mm);
        hipLaunchKernelGGL((normalize_k<true>), dim3(2048), dim3(256), 0, stream,
                           out, (const void*)mm, n4);
    }
}